// Round 1
// baseline (381.629 us; speedup 1.0000x reference)
//
#include <hip/hip_runtime.h>

#define NBOX 1024
#define KTOP 100
#define P 7
#define CONF_THR 0.4f
#define IOU_THR 0.5f

// ---------------- Kernel 1: per-batch sort + greedy NMS + compaction ----------------
__global__ __launch_bounds__(1024) void nms_kernel(
    const float* __restrict__ dets,   // (B, 1024, 6) cx,cy,w,h,conf,cls
    float* __restrict__ sel_boxes,    // (B, 100, 4) xyxy, ws
    int* __restrict__ n_valid)        // (B,) ws
{
    const int b   = blockIdx.x;
    const int tid = threadIdx.x;

    __shared__ float  skey[NBOX];          // scores, sorted
    __shared__ int    sidx[NBOX];          // original indices
    __shared__ float4 sbox[NBOX];          // sorted boxes (xyxy)
    __shared__ unsigned char supp[NBOX];   // suppression flags

    const float* db = dets + (size_t)b * NBOX * 6;

    skey[tid] = db[tid * 6 + 4];
    sidx[tid] = tid;
    supp[tid] = 0;
    __syncthreads();

    // Bitonic sort: descending by score, ties by original index ascending
    // (exactly reproduces stable argsort(-scores)).
    for (int k = 2; k <= NBOX; k <<= 1) {
        for (int j = k >> 1; j > 0; j >>= 1) {
            int i = tid;
            int ixj = i ^ j;
            if (ixj > i) {
                float si = skey[i], sj = skey[ixj];
                int   ai = sidx[i], aj = sidx[ixj];
                bool before = (si > sj) || (si == sj && ai < aj);
                bool want   = ((i & k) == 0);
                if (before != want) {
                    skey[i] = sj; skey[ixj] = si;
                    sidx[i] = aj; sidx[ixj] = ai;
                }
            }
            __syncthreads();
        }
    }

    // Gather sorted boxes, convert xywh -> xyxy (w/2 multiply is exact).
    {
        int oi = sidx[tid];
        float cx = db[oi * 6 + 0], cy = db[oi * 6 + 1];
        float w  = db[oi * 6 + 2], h  = db[oi * 6 + 3];
        float hw = __fmul_rn(w, 0.5f), hh = __fmul_rn(h, 0.5f);
        sbox[tid] = make_float4(__fsub_rn(cx, hw), __fsub_rn(cy, hh),
                                __fadd_rn(cx, hw), __fadd_rn(cy, hh));
    }
    __syncthreads();

    const float4 mybox  = sbox[tid];
    const float  my_area = __fmul_rn(__fsub_rn(mybox.z, mybox.x),
                                     __fsub_rn(mybox.w, mybox.y));

    // Greedy NMS. skey/supp reads at [i] are wave-uniform (shared broadcast),
    // so break/continue are non-divergent. One __syncthreads per KEPT box only.
    for (int i = 0; i < NBOX; ++i) {
        float si = skey[i];
        if (si <= CONF_THR) break;      // sorted: nothing after is valid
        if (supp[i]) continue;          // no writes since last sync -> safe read
        if (tid > i && !supp[tid]) {
            float4 a = sbox[i];
            float lx = fmaxf(a.x, mybox.x);
            float ly = fmaxf(a.y, mybox.y);
            float rx = fminf(a.z, mybox.z);
            float ry = fminf(a.w, mybox.w);
            float iw = fmaxf(__fsub_rn(rx, lx), 0.0f);
            float ih = fmaxf(__fsub_rn(ry, ly), 0.0f);
            float inter  = __fmul_rn(iw, ih);
            float area_a = __fmul_rn(__fsub_rn(a.z, a.x), __fsub_rn(a.w, a.y));
            // ((area_a + area_b) - inter) + 1e-7, exact np op order
            float denom = __fadd_rn(__fsub_rn(__fadd_rn(area_a, my_area), inter), 1e-7f);
            float iou   = __fdiv_rn(inter, denom);
            if (iou > IOU_THR) supp[tid] = 1;
        }
        __syncthreads();
    }
    __syncthreads();

    // Compact first <=100 kept boxes in sorted order (top_k equivalence).
    if (tid == 0) {
        int cnt = 0;
        float4* ob = (float4*)(sel_boxes + (size_t)b * KTOP * 4);
        for (int j = 0; j < NBOX && cnt < KTOP; ++j) {
            if (skey[j] <= CONF_THR) break;
            if (!supp[j]) { ob[cnt] = sbox[j]; ++cnt; }
        }
        n_valid[b] = cnt;
    }
}

// ---------------- Kernel 2: ROI pool (nearest, 7x7) + MLP 147->255->128->4 ----------------
__global__ __launch_bounds__(256) void roi_mlp_kernel(
    const float* __restrict__ x,          // (B, 3, 640, 640)
    const float* __restrict__ sel_boxes,  // (B, 100, 4)
    const int*   __restrict__ n_valid,    // (B,)
    const float* __restrict__ W1, const float* __restrict__ b1,   // (147,255),(255)
    const float* __restrict__ W2, const float* __restrict__ b2,   // (255,128),(128)
    const float* __restrict__ W3, const float* __restrict__ b3,   // (128,4),(4)
    float* __restrict__ out)              // (B, 100, 4)
{
    const int b   = blockIdx.y;
    const int kk  = blockIdx.x;
    const int tid = threadIdx.x;

    float* o = out + ((size_t)b * KTOP + kk) * 4;
    if (kk >= n_valid[b]) {               // uniform for whole block
        if (tid < 4) o[tid] = 0.0f;
        return;
    }

    __shared__ float crop[147];
    __shared__ float feat[255];
    __shared__ float hbuf[128];

    const float* bb = sel_boxes + ((size_t)b * KTOP + kk) * 4;
    const float x1 = bb[0], y1 = bb[1], x2 = bb[2], y2 = bb[3];

    if (tid < 147) {
        int c  = tid / 49;
        int r  = tid - c * 49;
        int py = r / 7;
        int px = r - py * 7;
        // xs = x1 + ((x2-x1) * (p+0.5)) / 7   -- exact np op order, no fma
        float fx = __fadd_rn(x1, __fdiv_rn(__fmul_rn(__fsub_rn(x2, x1), (float)px + 0.5f), 7.0f));
        float fy = __fadd_rn(y1, __fdiv_rn(__fmul_rn(__fsub_rn(y2, y1), (float)py + 0.5f), 7.0f));
        int xi = (int)fminf(fmaxf(fx, 0.0f), 639.0f);   // clip then trunc (>=0 -> floor)
        int yi = (int)fminf(fmaxf(fy, 0.0f), 639.0f);
        crop[tid] = x[(((size_t)b * 3 + c) * 640 + yi) * 640 + xi];
    }
    __syncthreads();

    if (tid < 255) {
        float acc = b1[tid];
        for (int i = 0; i < 147; ++i) acc += crop[i] * W1[i * 255 + tid];
        feat[tid] = acc;                   // NOTE: no activation on layer 1
    }
    __syncthreads();

    if (tid < 128) {
        float acc = b2[tid];
        for (int i = 0; i < 255; ++i) acc += feat[i] * W2[i * 128 + tid];
        hbuf[tid] = fmaxf(acc, 0.0f);      // relu
    }
    __syncthreads();

    if (tid < 4) {
        float acc = b3[tid];
        for (int i = 0; i < 128; ++i) acc += hbuf[i] * W3[i * 4 + tid];
        o[tid] = acc;                      // final layer: no activation
    }
}

extern "C" void kernel_launch(void* const* d_in, const int* in_sizes, int n_in,
                              void* d_out, int out_size, void* d_ws, size_t ws_size,
                              hipStream_t stream) {
    const float* x    = (const float*)d_in[0];
    const float* dets = (const float*)d_in[1];
    const float* W1   = (const float*)d_in[2];
    const float* b1   = (const float*)d_in[3];
    const float* W2   = (const float*)d_in[4];
    const float* b2   = (const float*)d_in[5];
    const float* W3   = (const float*)d_in[6];
    const float* b3   = (const float*)d_in[7];
    float* out = (float*)d_out;

    const int B = in_sizes[1] / (NBOX * 6);   // 16

    float* sel_boxes = (float*)d_ws;                                  // B*100*4 floats
    int*   n_valid   = (int*)((char*)d_ws + (size_t)B * KTOP * 4 * sizeof(float));

    nms_kernel<<<B, 1024, 0, stream>>>(dets, sel_boxes, n_valid);

    dim3 grid2(KTOP, B);
    roi_mlp_kernel<<<grid2, 256, 0, stream>>>(x, sel_boxes, n_valid,
                                              W1, b1, W2, b2, W3, b3, out);
}

// Round 4
// 373.905 us; speedup vs baseline: 1.0207x; 1.0207x over previous
//
#include <hip/hip_runtime.h>

#define NBOX 1024
#define KTOP 100
#define CONF_THR 0.4f
#define IOU_THR 0.5f
#define RPB 4     // rows per block in iou_mask_kernel
#define G 4       // ROIs per block in roi_mlp_kernel

typedef unsigned long long u64;

// ---------------- Kernel 1: rank sort (stable argsort by (score desc, idx asc)) ----------------
__global__ __launch_bounds__(1024) void sort_kernel(
    const float* __restrict__ dets,    // (B,1024,6)
    float4* __restrict__ sboxes,       // (B,1024) sorted xyxy
    int* __restrict__ nv_out)          // (B,) count of scores > CONF_THR
{
    const int b = blockIdx.x, t = threadIdx.x;
    __shared__ float skey[NBOX];
    const float* db = dets + (size_t)b * NBOX * 6;

    const float cx = db[t*6+0], cy = db[t*6+1];
    const float w  = db[t*6+2], h  = db[t*6+3];
    const float st = db[t*6+4];
    skey[t] = st;
    __syncthreads();

    int rank = 0;
    for (int j = 0; j < NBOX; ++j) {
        float sj = skey[j];                       // LDS broadcast (uniform addr)
        rank += (sj > st || (sj == st && j < t)) ? 1 : 0;
    }

    const float hw = __fmul_rn(w, 0.5f), hh = __fmul_rn(h, 0.5f);
    sboxes[(size_t)b*NBOX + rank] = make_float4(__fsub_rn(cx,hw), __fsub_rn(cy,hh),
                                                __fadd_rn(cx,hw), __fadd_rn(cy,hh));
    int cnt = __syncthreads_count(st > CONF_THR);
    if (t == 0) nv_out[b] = cnt;
}

// ---------------- Kernel 2: pairwise-IoU suppression bitmask rows ----------------
__global__ __launch_bounds__(256) void iou_mask_kernel(
    const float4* __restrict__ sboxes, // (B,1024)
    const int* __restrict__ nv,        // (B,)
    u64* __restrict__ mask)            // (B,1024,16) bit j of row i: j>i && IoU>thr
{
    const int b  = blockIdx.y;
    const int i0 = blockIdx.x * RPB;
    const int nvB = nv[b];
    if (i0 >= nvB) return;             // rows never read by scan
    const int tid = threadIdx.x;
    const int lane = tid & 63, wv = tid >> 6;

    const float4* sb = sboxes + (size_t)b * NBOX;
    float4 bi[RPB]; float ai[RPB];
    #pragma unroll
    for (int r = 0; r < RPB; ++r) {
        bi[r] = sb[min(i0 + r, NBOX - 1)];
        ai[r] = __fmul_rn(__fsub_rn(bi[r].z, bi[r].x), __fsub_rn(bi[r].w, bi[r].y));
    }
    u64* rowbase = mask + ((size_t)b * NBOX + i0) * 16;

    for (int c = 0; c < 4; ++c) {
        const int j = c * 256 + tid;
        const float4 bj = sb[j];
        const float aj = __fmul_rn(__fsub_rn(bj.z, bj.x), __fsub_rn(bj.w, bj.y));
        #pragma unroll
        for (int r = 0; r < RPB; ++r) {
            const int i = i0 + r;
            if (i >= nvB) break;       // uniform across block
            float lx = fmaxf(bi[r].x, bj.x), ly = fmaxf(bi[r].y, bj.y);
            float rx = fminf(bi[r].z, bj.z), ry = fminf(bi[r].w, bj.w);
            float iw = fmaxf(__fsub_rn(rx, lx), 0.0f);
            float ih = fmaxf(__fsub_rn(ry, ly), 0.0f);
            float inter = __fmul_rn(iw, ih);
            float denom = __fadd_rn(__fsub_rn(__fadd_rn(ai[r], aj), inter), 1e-7f);
            bool pred = (j > i) && (__fdiv_rn(inter, denom) > IOU_THR);
            u64 m = __ballot(pred);
            if (lane == 0) rowbase[(size_t)r * 16 + c * 4 + wv] = m;
        }
    }
}

// ---------------- Kernel 3: serial greedy scan over bitmasks + compaction ----------------
__global__ __launch_bounds__(64) void scan_kernel(
    const float4* __restrict__ sboxes,
    const u64* __restrict__ mask,
    const int* __restrict__ nv,
    float4* __restrict__ sel,          // (B,100)
    int* __restrict__ nkeep)           // (B,) min(kept,100)
{
    const int b = blockIdx.x, lane = threadIdx.x;
    const int nvB = nv[b];
    const u64* mb = mask + (size_t)b * NBOX * 16;

    u64 sw = 0, kw = 0;                // lane l (<16) holds suppression/keep word l
    u64 pre[8];
    #pragma unroll
    for (int u = 0; u < 8; ++u)
        pre[u] = (u < nvB && lane < 16) ? mb[(size_t)u * 16 + lane] : 0ull;

    for (int i0 = 0; i0 < NBOX; i0 += 8) {
        if (i0 >= nvB) break;
        #pragma unroll
        for (int u = 0; u < 8; ++u) {          // fully unrolled: pre[u] stays in regs
            const int i = i0 + u;
            u64 row = pre[u];
            const int ip = i + 8;
            pre[u] = (ip < nvB && lane < 16) ? mb[(size_t)ip * 16 + lane] : 0ull;
            if (i < nvB) {
                const int wsel = i >> 6;
                u64 sword = __shfl(sw, wsel);  // uniform result
                if (!((sword >> (i & 63)) & 1ull)) {
                    sw |= row;
                    if (lane == wsel) kw |= (1ull << (i & 63));
                }
            }
        }
    }

    // wave-parallel compaction: rank = exclusive popcount prefix
    int cnt = (lane < 16) ? __popcll(kw) : 0;
    int pfx = cnt;
    #pragma unroll
    for (int d = 1; d < 16; d <<= 1) { int t2 = __shfl_up(pfx, d); if (lane >= d) pfx += t2; }
    const int excl = pfx - cnt;
    const int total = __shfl(pfx, 15);

    const float4* sb = sboxes + (size_t)b * NBOX;
    float4* selb = sel + (size_t)b * KTOP;
    for (int w = 0; w < 16; ++w) {
        u64 kwW = __shfl(kw, w);
        int bR  = __shfl(excl, w);
        if ((kwW >> lane) & 1ull) {
            int rank = bR + __popcll(kwW & ((1ull << lane) - 1ull));
            if (rank < KTOP) selb[rank] = sb[w * 64 + lane];
        }
    }
    for (int r = total + lane; r < KTOP; r += 64) selb[r] = make_float4(0,0,0,0);
    if (lane == 0) nkeep[b] = total < KTOP ? total : KTOP;
}

// ---------------- Kernel 4: ROI pool + MLP, G ROIs/block for W reuse ----------------
__global__ __launch_bounds__(256) void roi_mlp_kernel(
    const float* __restrict__ x,          // (B,3,640,640)
    const float4* __restrict__ sel,       // (B,100)
    const int* __restrict__ nkeep,        // (B,)
    const float* __restrict__ W1, const float* __restrict__ b1,
    const float* __restrict__ W2, const float* __restrict__ b2,
    const float* __restrict__ W3, const float* __restrict__ b3,
    float* __restrict__ out)              // (B,100,4)
{
    const int b = blockIdx.y, k0 = blockIdx.x * G, tid = threadIdx.x;
    __shared__ float crop[G][147];
    __shared__ float feat[G][255];
    __shared__ float hb[G][128];
    const int nvB = nkeep[b];
    const float4* selb = sel + (size_t)b * KTOP;

    for (int task = tid; task < G * 147; task += 256) {
        int g = task / 147, r = task - g * 147;
        int c = r / 49, rr = r - c * 49;
        int py = rr / 7, px = rr - py * 7;
        float4 bb = selb[k0 + g];
        float fx = __fadd_rn(bb.x, __fdiv_rn(__fmul_rn(__fsub_rn(bb.z, bb.x), (float)px + 0.5f), 7.0f));
        float fy = __fadd_rn(bb.y, __fdiv_rn(__fmul_rn(__fsub_rn(bb.w, bb.y), (float)py + 0.5f), 7.0f));
        int xi = (int)fminf(fmaxf(fx, 0.0f), 639.0f);
        int yi = (int)fminf(fmaxf(fy, 0.0f), 639.0f);
        crop[g][r] = x[(((size_t)b * 3 + c) * 640 + yi) * 640 + xi];
    }
    __syncthreads();

    if (tid < 255) {                       // layer 1: 147 -> 255, no activation
        float a0 = b1[tid], a1 = a0, a2 = a0, a3 = a0;
        for (int i = 0; i < 147; ++i) {
            float w = W1[i * 255 + tid];
            a0 += crop[0][i] * w; a1 += crop[1][i] * w;
            a2 += crop[2][i] * w; a3 += crop[3][i] * w;
        }
        feat[0][tid] = a0; feat[1][tid] = a1; feat[2][tid] = a2; feat[3][tid] = a3;
    }
    __syncthreads();

    {                                      // layer 2: 255 -> 128, relu
        const int col = tid & 127, g0 = (tid >> 7) * 2;
        float a0 = b2[col], a1 = a0;
        for (int i = 0; i < 255; ++i) {
            float w = W2[i * 128 + col];
            a0 += feat[g0][i] * w; a1 += feat[g0 + 1][i] * w;
        }
        hb[g0][col] = fmaxf(a0, 0.0f); hb[g0 + 1][col] = fmaxf(a1, 0.0f);
    }
    __syncthreads();

    if (tid < 4 * G) {                     // layer 3: 128 -> 4
        const int g = tid >> 2, o = tid & 3;
        float acc = b3[o];
        for (int i = 0; i < 128; ++i) acc += hb[g][i] * W3[i * 4 + o];
        const int k = k0 + g;
        out[((size_t)b * KTOP + k) * 4 + o] = (k < nvB) ? acc : 0.0f;
    }
}

extern "C" void kernel_launch(void* const* d_in, const int* in_sizes, int n_in,
                              void* d_out, int out_size, void* d_ws, size_t ws_size,
                              hipStream_t stream) {
    const float* x    = (const float*)d_in[0];
    const float* dets = (const float*)d_in[1];
    const float* W1   = (const float*)d_in[2];
    const float* b1   = (const float*)d_in[3];
    const float* W2   = (const float*)d_in[4];
    const float* b2   = (const float*)d_in[5];
    const float* W3   = (const float*)d_in[6];
    const float* b3   = (const float*)d_in[7];
    float* out = (float*)d_out;

    const int B = in_sizes[1] / (NBOX * 6);   // 16

    // workspace layout (16B-aligned chunks)
    float4* sboxes = (float4*)d_ws;                       // B*1024 float4 = 256 KB
    float4* sel    = sboxes + (size_t)B * NBOX;           // B*100  float4 = 25.6 KB
    u64*    mask   = (u64*)(sel + (size_t)B * KTOP);      // B*1024*16 u64 = 2 MB
    int*    nv     = (int*)(mask + (size_t)B * NBOX * 16);
    int*    nkeep  = nv + B;

    sort_kernel<<<B, NBOX, 0, stream>>>(dets, sboxes, nv);

    dim3 gmask(NBOX / RPB, B);
    iou_mask_kernel<<<gmask, 256, 0, stream>>>(sboxes, nv, mask);

    scan_kernel<<<B, 64, 0, stream>>>(sboxes, mask, nv, sel, nkeep);

    dim3 groi(KTOP / G, B);
    roi_mlp_kernel<<<groi, 256, 0, stream>>>(x, sel, nkeep,
                                             W1, b1, W2, b2, W3, b3, out);
}

// Round 6
// 213.153 us; speedup vs baseline: 1.7904x; 1.7542x over previous
//
#include <hip/hip_runtime.h>

#define NBOX 1024
#define KTOP 100
#define CONF_THR 0.4f
#define IOU_THR 0.5f
#define RPB 4       // rows per block in iou_mask_kernel
#define G 4         // ROIs per block in roi_mlp_kernel
#define CHUNK 480   // mask rows staged in LDS per scan chunk (60 KB)

typedef unsigned long long u64;

// ---------------- Kernel 1: rank sort (stable argsort by (score desc, idx asc)) ----------------
__global__ __launch_bounds__(1024) void sort_kernel(
    const float* __restrict__ dets,    // (B,1024,6)
    float4* __restrict__ sboxes,       // (B,1024) sorted xyxy
    int* __restrict__ nv_out)          // (B,) count of scores > CONF_THR
{
    const int b = blockIdx.x, t = threadIdx.x;
    __shared__ float skey[NBOX];
    const float* db = dets + (size_t)b * NBOX * 6;

    const float cx = db[t*6+0], cy = db[t*6+1];
    const float w  = db[t*6+2], h  = db[t*6+3];
    const float st = db[t*6+4];
    skey[t] = st;
    __syncthreads();

    int rank = 0;
    for (int j = 0; j < NBOX; ++j) {
        float sj = skey[j];                       // LDS broadcast (uniform addr)
        rank += (sj > st || (sj == st && j < t)) ? 1 : 0;
    }

    const float hw = __fmul_rn(w, 0.5f), hh = __fmul_rn(h, 0.5f);
    sboxes[(size_t)b*NBOX + rank] = make_float4(__fsub_rn(cx,hw), __fsub_rn(cy,hh),
                                                __fadd_rn(cx,hw), __fadd_rn(cy,hh));
    int cnt = __syncthreads_count(st > CONF_THR);
    if (t == 0) nv_out[b] = cnt;
}

// ---------------- Kernel 2: pairwise-IoU suppression bitmask rows ----------------
__global__ __launch_bounds__(256) void iou_mask_kernel(
    const float4* __restrict__ sboxes, // (B,1024)
    const int* __restrict__ nv,        // (B,)
    u64* __restrict__ mask)            // (B,1024,16) bit j of row i: j>i && IoU>thr
{
    const int b  = blockIdx.y;
    const int i0 = blockIdx.x * RPB;
    const int nvB = nv[b];
    if (i0 >= nvB) return;             // rows never read by scan
    const int tid = threadIdx.x;
    const int lane = tid & 63, wv = tid >> 6;

    const float4* sb = sboxes + (size_t)b * NBOX;
    float4 bi[RPB]; float ai[RPB];
    #pragma unroll
    for (int r = 0; r < RPB; ++r) {
        bi[r] = sb[min(i0 + r, NBOX - 1)];
        ai[r] = __fmul_rn(__fsub_rn(bi[r].z, bi[r].x), __fsub_rn(bi[r].w, bi[r].y));
    }
    u64* rowbase = mask + ((size_t)b * NBOX + i0) * 16;

    for (int c = 0; c < 4; ++c) {
        const int j = c * 256 + tid;
        const float4 bj = sb[j];
        const float aj = __fmul_rn(__fsub_rn(bj.z, bj.x), __fsub_rn(bj.w, bj.y));
        #pragma unroll
        for (int r = 0; r < RPB; ++r) {
            const int i = i0 + r;
            if (i >= nvB) break;       // uniform across block
            float lx = fmaxf(bi[r].x, bj.x), ly = fmaxf(bi[r].y, bj.y);
            float rx = fminf(bi[r].z, bj.z), ry = fminf(bi[r].w, bj.w);
            float iw = fmaxf(__fsub_rn(rx, lx), 0.0f);
            float ih = fmaxf(__fsub_rn(ry, ly), 0.0f);
            float inter = __fmul_rn(iw, ih);
            float denom = __fadd_rn(__fsub_rn(__fadd_rn(ai[r], aj), inter), 1e-7f);
            bool pred = (j > i) && (__fdiv_rn(inter, denom) > IOU_THR);
            u64 m = __ballot(pred);
            if (lane == 0) rowbase[(size_t)r * 16 + c * 4 + wv] = m;
        }
    }
}

// ---------------- Kernel 3: greedy scan — LDS-staged chunks + early exit at 100 keeps ----------------
__global__ __launch_bounds__(1024) void scan_kernel(
    const float4* __restrict__ sboxes,
    const u64* __restrict__ mask,
    const int* __restrict__ nv,
    float4* __restrict__ sel,          // (B,100)
    int* __restrict__ nkeep)           // (B,)
{
    const int b = blockIdx.x, tid = threadIdx.x;
    const int lane = tid & 63;
    const int nvB = nv[b];
    const u64* mb = mask + (size_t)b * NBOX * 16;

    __shared__ u64 lm[CHUNK * 16];     // 60 KB staged mask rows
    __shared__ int s_stop;

    u64 sw = 0, kw = 0;                // wave0: lane l (<16) holds supp/keep word l
    int kcnt = 0;
    if (tid == 0) s_stop = 0;

    for (int base = 0; base < nvB; base += CHUNK) {
        const int cn = min(CHUNK, nvB - base);
        // cooperative coalesced stage: HBM/L3 latency paid once per chunk
        for (int idx = tid; idx < cn * 16; idx += 1024)
            lm[idx] = mb[(size_t)base * 16 + idx];
        __syncthreads();

        if (tid < 64) {
            u64 pre[8];
            #pragma unroll
            for (int u = 0; u < 8; ++u)
                pre[u] = (u < cn && lane < 16) ? lm[u * 16 + lane] : 0ull;
            for (int r0 = 0; r0 < cn && kcnt < KTOP; r0 += 8) {
                #pragma unroll
                for (int u = 0; u < 8; ++u) {   // static indexing: pre[] stays in regs
                    const int r = r0 + u;
                    u64 row = pre[u];
                    const int rp = r + 8;
                    pre[u] = (rp < cn && lane < 16) ? lm[rp * 16 + lane] : 0ull;
                    if (r < cn && kcnt < KTOP) {
                        const int i = base + r;
                        const int wsel = i >> 6;
                        u64 sword = __shfl(sw, wsel);          // uniform result
                        if (!((sword >> (i & 63)) & 1ull)) {   // not suppressed -> keep
                            sw |= row;
                            if (lane == wsel) kw |= (1ull << (i & 63));
                            ++kcnt;                            // wave-uniform
                        }
                    }
                }
            }
            if (tid == 0 && kcnt >= KTOP) s_stop = 1;  // first 100 kept == top-K: rest is dead
        }
        __syncthreads();
        if (s_stop) break;             // uniform across block
    }

    if (tid < 64) {
        // wave-parallel compaction: rank = exclusive popcount prefix
        int cnt = (lane < 16) ? __popcll(kw) : 0;
        int pfx = cnt;
        #pragma unroll
        for (int d = 1; d < 16; d <<= 1) { int t2 = __shfl_up(pfx, d); if (lane >= d) pfx += t2; }
        const int excl = pfx - cnt;
        const int total = __shfl(pfx, 15);     // == kcnt <= 100

        const float4* sb = sboxes + (size_t)b * NBOX;
        float4* selb = sel + (size_t)b * KTOP;
        for (int w = 0; w < 16; ++w) {
            u64 kwW = __shfl(kw, w);
            int bR  = __shfl(excl, w);
            if ((kwW >> lane) & 1ull) {
                int rank = bR + __popcll(kwW & ((1ull << lane) - 1ull));
                if (rank < KTOP) selb[rank] = sb[w * 64 + lane];
            }
        }
        for (int r = total + lane; r < KTOP; r += 64) selb[r] = make_float4(0,0,0,0);
        if (lane == 0) nkeep[b] = total < KTOP ? total : KTOP;
    }
}

// ---------------- Kernel 4: ROI pool + MLP, G ROIs/block for W reuse ----------------
__global__ __launch_bounds__(256) void roi_mlp_kernel(
    const float* __restrict__ x,          // (B,3,640,640)
    const float4* __restrict__ sel,       // (B,100)
    const int* __restrict__ nkeep,        // (B,)
    const float* __restrict__ W1, const float* __restrict__ b1,
    const float* __restrict__ W2, const float* __restrict__ b2,
    const float* __restrict__ W3, const float* __restrict__ b3,
    float* __restrict__ out)              // (B,100,4)
{
    const int b = blockIdx.y, k0 = blockIdx.x * G, tid = threadIdx.x;
    __shared__ float crop[G][147];
    __shared__ float feat[G][255];
    __shared__ float hb[G][128];
    const int nvB = nkeep[b];
    const float4* selb = sel + (size_t)b * KTOP;

    for (int task = tid; task < G * 147; task += 256) {
        int g = task / 147, r = task - g * 147;
        int c = r / 49, rr = r - c * 49;
        int py = rr / 7, px = rr - py * 7;
        float4 bb = selb[k0 + g];
        float fx = __fadd_rn(bb.x, __fdiv_rn(__fmul_rn(__fsub_rn(bb.z, bb.x), (float)px + 0.5f), 7.0f));
        float fy = __fadd_rn(bb.y, __fdiv_rn(__fmul_rn(__fsub_rn(bb.w, bb.y), (float)py + 0.5f), 7.0f));
        int xi = (int)fminf(fmaxf(fx, 0.0f), 639.0f);
        int yi = (int)fminf(fmaxf(fy, 0.0f), 639.0f);
        crop[g][r] = x[(((size_t)b * 3 + c) * 640 + yi) * 640 + xi];
    }
    __syncthreads();

    if (tid < 255) {                       // layer 1: 147 -> 255, no activation
        float a0 = b1[tid], a1 = a0, a2 = a0, a3 = a0;
        for (int i = 0; i < 147; ++i) {
            float w = W1[i * 255 + tid];
            a0 += crop[0][i] * w; a1 += crop[1][i] * w;
            a2 += crop[2][i] * w; a3 += crop[3][i] * w;
        }
        feat[0][tid] = a0; feat[1][tid] = a1; feat[2][tid] = a2; feat[3][tid] = a3;
    }
    __syncthreads();

    {                                      // layer 2: 255 -> 128, relu
        const int col = tid & 127, g0 = (tid >> 7) * 2;
        float a0 = b2[col], a1 = a0;
        for (int i = 0; i < 255; ++i) {
            float w = W2[i * 128 + col];
            a0 += feat[g0][i] * w; a1 += feat[g0 + 1][i] * w;
        }
        hb[g0][col] = fmaxf(a0, 0.0f); hb[g0 + 1][col] = fmaxf(a1, 0.0f);
    }
    __syncthreads();

    if (tid < 4 * G) {                     // layer 3: 128 -> 4
        const int g = tid >> 2, o = tid & 3;
        float acc = b3[o];
        for (int i = 0; i < 128; ++i) acc += hb[g][i] * W3[i * 4 + o];
        const int k = k0 + g;
        out[((size_t)b * KTOP + k) * 4 + o] = (k < nvB) ? acc : 0.0f;
    }
}

extern "C" void kernel_launch(void* const* d_in, const int* in_sizes, int n_in,
                              void* d_out, int out_size, void* d_ws, size_t ws_size,
                              hipStream_t stream) {
    const float* x    = (const float*)d_in[0];
    const float* dets = (const float*)d_in[1];
    const float* W1   = (const float*)d_in[2];
    const float* b1   = (const float*)d_in[3];
    const float* W2   = (const float*)d_in[4];
    const float* b2   = (const float*)d_in[5];
    const float* W3   = (const float*)d_in[6];
    const float* b3   = (const float*)d_in[7];
    float* out = (float*)d_out;

    const int B = in_sizes[1] / (NBOX * 6);   // 16

    // workspace layout (16B-aligned chunks)
    float4* sboxes = (float4*)d_ws;                       // B*1024 float4 = 256 KB
    float4* sel    = sboxes + (size_t)B * NBOX;           // B*100  float4 = 25.6 KB
    u64*    mask   = (u64*)(sel + (size_t)B * KTOP);      // B*1024*16 u64 = 2 MB
    int*    nv     = (int*)(mask + (size_t)B * NBOX * 16);
    int*    nkeep  = nv + B;

    sort_kernel<<<B, NBOX, 0, stream>>>(dets, sboxes, nv);

    dim3 gmask(NBOX / RPB, B);
    iou_mask_kernel<<<gmask, 256, 0, stream>>>(sboxes, nv, mask);

    scan_kernel<<<B, 1024, 0, stream>>>(sboxes, mask, nv, sel, nkeep);

    dim3 groi(KTOP / G, B);
    roi_mlp_kernel<<<groi, 256, 0, stream>>>(x, sel, nkeep,
                                             W1, b1, W2, b2, W3, b3, out);
}

// Round 7
// 189.549 us; speedup vs baseline: 2.0134x; 1.1245x over previous
//
#include <hip/hip_runtime.h>

#define NBOX 1024
#define KTOP 100
#define CONF_THR 0.4f
#define IOU_THR 0.5f
#define RPB 4       // rows per block in iou_mask_kernel
#define G 4         // ROIs per block in roi_mlp_kernel
#define CHUNK 480   // mask rows staged in LDS per scan chunk (60 KB)

typedef unsigned long long u64;

// ---------------- Kernel 1: bitonic sort (stable argsort by (score desc, idx asc)) ----------------
// Rank-sort variant regressed: 1024 uniform ds_read per thread = 16K LDS inst on one CU
// (~38 us). Bitonic is 55 barrier'd stages (~5 us).
__global__ __launch_bounds__(1024) void sort_kernel(
    const float* __restrict__ dets,    // (B,1024,6)
    float4* __restrict__ sboxes,       // (B,1024) sorted xyxy
    int* __restrict__ nv_out)          // (B,) count of scores > CONF_THR
{
    const int b = blockIdx.x, t = threadIdx.x;
    __shared__ float skey[NBOX];
    __shared__ int   sidx[NBOX];
    const float* db = dets + (size_t)b * NBOX * 6;

    const float st = db[t*6+4];
    skey[t] = st;
    sidx[t] = t;
    __syncthreads();

    // Descending by score, ties by original index ascending == stable argsort(-s).
    for (int k = 2; k <= NBOX; k <<= 1) {
        for (int j = k >> 1; j > 0; j >>= 1) {
            int i = t, ixj = i ^ j;
            if (ixj > i) {
                float si = skey[i], sj = skey[ixj];
                int   ai = sidx[i], aj = sidx[ixj];
                bool before = (si > sj) || (si == sj && ai < aj);
                bool want   = ((i & k) == 0);
                if (before != want) {
                    skey[i] = sj; skey[ixj] = si;
                    sidx[i] = aj; sidx[ixj] = ai;
                }
            }
            __syncthreads();
        }
    }

    // Gather box by sorted index, xywh -> xyxy (mul by 0.5 == div by 2, exact).
    {
        int oi = sidx[t];
        float cx = db[oi*6+0], cy = db[oi*6+1];
        float w  = db[oi*6+2], h  = db[oi*6+3];
        float hw = __fmul_rn(w, 0.5f), hh = __fmul_rn(h, 0.5f);
        sboxes[(size_t)b*NBOX + t] = make_float4(__fsub_rn(cx,hw), __fsub_rn(cy,hh),
                                                 __fadd_rn(cx,hw), __fadd_rn(cy,hh));
    }
    int cnt = __syncthreads_count(st > CONF_THR);
    if (t == 0) nv_out[b] = cnt;
}

// ---------------- Kernel 2: pairwise-IoU suppression bitmask rows ----------------
__global__ __launch_bounds__(256) void iou_mask_kernel(
    const float4* __restrict__ sboxes, // (B,1024)
    const int* __restrict__ nv,        // (B,)
    u64* __restrict__ mask)            // (B,1024,16) bit j of row i: j>i && IoU>thr
{
    const int b  = blockIdx.y;
    const int i0 = blockIdx.x * RPB;
    const int nvB = nv[b];
    if (i0 >= nvB) return;             // rows never read by scan
    const int tid = threadIdx.x;
    const int lane = tid & 63, wv = tid >> 6;

    const float4* sb = sboxes + (size_t)b * NBOX;
    float4 bi[RPB]; float ai[RPB];
    #pragma unroll
    for (int r = 0; r < RPB; ++r) {
        bi[r] = sb[min(i0 + r, NBOX - 1)];
        ai[r] = __fmul_rn(__fsub_rn(bi[r].z, bi[r].x), __fsub_rn(bi[r].w, bi[r].y));
    }
    u64* rowbase = mask + ((size_t)b * NBOX + i0) * 16;

    for (int c = 0; c < 4; ++c) {
        const int j = c * 256 + tid;
        const float4 bj = sb[j];
        const float aj = __fmul_rn(__fsub_rn(bj.z, bj.x), __fsub_rn(bj.w, bj.y));
        #pragma unroll
        for (int r = 0; r < RPB; ++r) {
            const int i = i0 + r;
            if (i >= nvB) break;       // uniform across block
            float lx = fmaxf(bi[r].x, bj.x), ly = fmaxf(bi[r].y, bj.y);
            float rx = fminf(bi[r].z, bj.z), ry = fminf(bi[r].w, bj.w);
            float iw = fmaxf(__fsub_rn(rx, lx), 0.0f);
            float ih = fmaxf(__fsub_rn(ry, ly), 0.0f);
            float inter = __fmul_rn(iw, ih);
            float denom = __fadd_rn(__fsub_rn(__fadd_rn(ai[r], aj), inter), 1e-7f);
            bool pred = (j > i) && (__fdiv_rn(inter, denom) > IOU_THR);
            u64 m = __ballot(pred);
            if (lane == 0) rowbase[(size_t)r * 16 + c * 4 + wv] = m;
        }
    }
}

// ---------------- Kernel 3: greedy scan — LDS-staged chunks + early exit at 100 keeps ----------------
__global__ __launch_bounds__(1024) void scan_kernel(
    const float4* __restrict__ sboxes,
    const u64* __restrict__ mask,
    const int* __restrict__ nv,
    float4* __restrict__ sel,          // (B,100)
    int* __restrict__ nkeep)           // (B,)
{
    const int b = blockIdx.x, tid = threadIdx.x;
    const int lane = tid & 63;
    const int nvB = nv[b];
    const u64* mb = mask + (size_t)b * NBOX * 16;

    __shared__ u64 lm[CHUNK * 16];     // 60 KB staged mask rows
    __shared__ int s_stop;

    u64 sw = 0, kw = 0;                // wave0: lane l (<16) holds supp/keep word l
    int kcnt = 0;
    if (tid == 0) s_stop = 0;

    for (int base = 0; base < nvB; base += CHUNK) {
        const int cn = min(CHUNK, nvB - base);
        // cooperative coalesced stage: HBM/L3 latency paid once per chunk
        for (int idx = tid; idx < cn * 16; idx += 1024)
            lm[idx] = mb[(size_t)base * 16 + idx];
        __syncthreads();

        if (tid < 64) {
            u64 pre[8];
            #pragma unroll
            for (int u = 0; u < 8; ++u)
                pre[u] = (u < cn && lane < 16) ? lm[u * 16 + lane] : 0ull;
            for (int r0 = 0; r0 < cn && kcnt < KTOP; r0 += 8) {
                #pragma unroll
                for (int u = 0; u < 8; ++u) {   // static indexing: pre[] stays in regs
                    const int r = r0 + u;
                    u64 row = pre[u];
                    const int rp = r + 8;
                    pre[u] = (rp < cn && lane < 16) ? lm[rp * 16 + lane] : 0ull;
                    if (r < cn && kcnt < KTOP) {
                        const int i = base + r;
                        const int wsel = i >> 6;
                        u64 sword = __shfl(sw, wsel);          // uniform result
                        if (!((sword >> (i & 63)) & 1ull)) {   // not suppressed -> keep
                            sw |= row;
                            if (lane == wsel) kw |= (1ull << (i & 63));
                            ++kcnt;                            // wave-uniform
                        }
                    }
                }
            }
            if (tid == 0 && kcnt >= KTOP) s_stop = 1;  // first 100 kept == top-K: rest is dead
        }
        __syncthreads();
        if (s_stop) break;             // uniform across block
    }

    if (tid < 64) {
        // wave-parallel compaction: rank = exclusive popcount prefix
        int cnt = (lane < 16) ? __popcll(kw) : 0;
        int pfx = cnt;
        #pragma unroll
        for (int d = 1; d < 16; d <<= 1) { int t2 = __shfl_up(pfx, d); if (lane >= d) pfx += t2; }
        const int excl = pfx - cnt;
        const int total = __shfl(pfx, 15);     // == kcnt <= 100

        const float4* sb = sboxes + (size_t)b * NBOX;
        float4* selb = sel + (size_t)b * KTOP;
        for (int w = 0; w < 16; ++w) {
            u64 kwW = __shfl(kw, w);
            int bR  = __shfl(excl, w);
            if ((kwW >> lane) & 1ull) {
                int rank = bR + __popcll(kwW & ((1ull << lane) - 1ull));
                if (rank < KTOP) selb[rank] = sb[w * 64 + lane];
            }
        }
        for (int r = total + lane; r < KTOP; r += 64) selb[r] = make_float4(0,0,0,0);
        if (lane == 0) nkeep[b] = total < KTOP ? total : KTOP;
    }
}

// ---------------- Kernel 4: ROI pool + MLP, G ROIs/block for W reuse ----------------
__global__ __launch_bounds__(256) void roi_mlp_kernel(
    const float* __restrict__ x,          // (B,3,640,640)
    const float4* __restrict__ sel,       // (B,100)
    const int* __restrict__ nkeep,        // (B,)
    const float* __restrict__ W1, const float* __restrict__ b1,
    const float* __restrict__ W2, const float* __restrict__ b2,
    const float* __restrict__ W3, const float* __restrict__ b3,
    float* __restrict__ out)              // (B,100,4)
{
    const int b = blockIdx.y, k0 = blockIdx.x * G, tid = threadIdx.x;
    __shared__ float crop[G][147];
    __shared__ float feat[G][255];
    __shared__ float hb[G][128];
    const int nvB = nkeep[b];
    const float4* selb = sel + (size_t)b * KTOP;

    for (int task = tid; task < G * 147; task += 256) {
        int g = task / 147, r = task - g * 147;
        int c = r / 49, rr = r - c * 49;
        int py = rr / 7, px = rr - py * 7;
        float4 bb = selb[k0 + g];
        float fx = __fadd_rn(bb.x, __fdiv_rn(__fmul_rn(__fsub_rn(bb.z, bb.x), (float)px + 0.5f), 7.0f));
        float fy = __fadd_rn(bb.y, __fdiv_rn(__fmul_rn(__fsub_rn(bb.w, bb.y), (float)py + 0.5f), 7.0f));
        int xi = (int)fminf(fmaxf(fx, 0.0f), 639.0f);
        int yi = (int)fminf(fmaxf(fy, 0.0f), 639.0f);
        crop[g][r] = x[(((size_t)b * 3 + c) * 640 + yi) * 640 + xi];
    }
    __syncthreads();

    if (tid < 255) {                       // layer 1: 147 -> 255, no activation
        float a0 = b1[tid], a1 = a0, a2 = a0, a3 = a0;
        for (int i = 0; i < 147; ++i) {
            float w = W1[i * 255 + tid];
            a0 += crop[0][i] * w; a1 += crop[1][i] * w;
            a2 += crop[2][i] * w; a3 += crop[3][i] * w;
        }
        feat[0][tid] = a0; feat[1][tid] = a1; feat[2][tid] = a2; feat[3][tid] = a3;
    }
    __syncthreads();

    {                                      // layer 2: 255 -> 128, relu
        const int col = tid & 127, g0 = (tid >> 7) * 2;
        float a0 = b2[col], a1 = a0;
        for (int i = 0; i < 255; ++i) {
            float w = W2[i * 128 + col];
            a0 += feat[g0][i] * w; a1 += feat[g0 + 1][i] * w;
        }
        hb[g0][col] = fmaxf(a0, 0.0f); hb[g0 + 1][col] = fmaxf(a1, 0.0f);
    }
    __syncthreads();

    if (tid < 4 * G) {                     // layer 3: 128 -> 4
        const int g = tid >> 2, o = tid & 3;
        float acc = b3[o];
        for (int i = 0; i < 128; ++i) acc += hb[g][i] * W3[i * 4 + o];
        const int k = k0 + g;
        out[((size_t)b * KTOP + k) * 4 + o] = (k < nvB) ? acc : 0.0f;
    }
}

extern "C" void kernel_launch(void* const* d_in, const int* in_sizes, int n_in,
                              void* d_out, int out_size, void* d_ws, size_t ws_size,
                              hipStream_t stream) {
    const float* x    = (const float*)d_in[0];
    const float* dets = (const float*)d_in[1];
    const float* W1   = (const float*)d_in[2];
    const float* b1   = (const float*)d_in[3];
    const float* W2   = (const float*)d_in[4];
    const float* b2   = (const float*)d_in[5];
    const float* W3   = (const float*)d_in[6];
    const float* b3   = (const float*)d_in[7];
    float* out = (float*)d_out;

    const int B = in_sizes[1] / (NBOX * 6);   // 16

    // workspace layout (16B-aligned chunks)
    float4* sboxes = (float4*)d_ws;                       // B*1024 float4 = 256 KB
    float4* sel    = sboxes + (size_t)B * NBOX;           // B*100  float4 = 25.6 KB
    u64*    mask   = (u64*)(sel + (size_t)B * KTOP);      // B*1024*16 u64 = 2 MB
    int*    nv     = (int*)(mask + (size_t)B * NBOX * 16);
    int*    nkeep  = nv + B;

    sort_kernel<<<B, NBOX, 0, stream>>>(dets, sboxes, nv);

    dim3 gmask(NBOX / RPB, B);
    iou_mask_kernel<<<gmask, 256, 0, stream>>>(sboxes, nv, mask);

    scan_kernel<<<B, 1024, 0, stream>>>(sboxes, mask, nv, sel, nkeep);

    dim3 groi(KTOP / G, B);
    roi_mlp_kernel<<<groi, 256, 0, stream>>>(x, sel, nkeep,
                                             W1, b1, W2, b2, W3, b3, out);
}

// Round 8
// 184.655 us; speedup vs baseline: 2.0667x; 1.0265x over previous
//
#include <hip/hip_runtime.h>

#define NBOX 1024
#define KTOP 100
#define CONF_THR 0.4f
#define IOU_THR 0.5f
#define RPB 8       // rows per block in iou_mask_kernel
#define G 4         // ROIs per block in roi_mlp_kernel
#define CHUNK 256   // mask rows staged in LDS per scan chunk (32 KB)

typedef unsigned long long u64;

// ---------------- Kernel 1: hybrid shfl/LDS bitonic sort ----------------
// Stable argsort by (score desc, idx asc). Stages with j<64 are in-register
// shfl_xor compare-exchanges (no barrier); only j>=64 stages go through LDS
// (10 of 55 stages). keepMine = ((cmp(mine,partner)==want) == amLowerPos).
__global__ __launch_bounds__(1024) void sort_kernel(
    const float* __restrict__ dets,    // (B,1024,6)
    float4* __restrict__ sboxes,       // (B,1024) sorted xyxy
    int* __restrict__ nv_out)          // (B,) count of scores > CONF_THR
{
    const int b = blockIdx.x, t = threadIdx.x;
    __shared__ float skey[NBOX];
    __shared__ int   sidx[NBOX];
    const float* db = dets + (size_t)b * NBOX * 6;

    const float st = db[t*6+4];
    float mk = st;     // my key
    int   mi = t;      // my original index

    // k = 2..64: fully in-wave
    #pragma unroll
    for (int k = 2; k <= 64; k <<= 1) {
        const bool want = ((t & k) == 0);
        for (int j = k >> 1; j > 0; j >>= 1) {
            float pk = __shfl_xor(mk, j);
            int   pi = __shfl_xor(mi, j);
            bool cmp_mp = (mk > pk) || (mk == pk && mi < pi);
            bool low = ((t & j) == 0);
            if ((cmp_mp == want) != low) { mk = pk; mi = pi; }
        }
    }
    // k = 128..1024: j>=64 via LDS, j<64 via shfl
    for (int k = 128; k <= NBOX; k <<= 1) {
        const bool want = ((t & k) == 0);
        for (int j = k >> 1; j >= 64; j >>= 1) {
            skey[t] = mk; sidx[t] = mi;
            __syncthreads();
            float pk = skey[t ^ j];
            int   pi = sidx[t ^ j];
            bool cmp_mp = (mk > pk) || (mk == pk && mi < pi);
            bool low = ((t & j) == 0);
            if ((cmp_mp == want) != low) { mk = pk; mi = pi; }
            __syncthreads();
        }
        for (int j = 32; j > 0; j >>= 1) {
            float pk = __shfl_xor(mk, j);
            int   pi = __shfl_xor(mi, j);
            bool cmp_mp = (mk > pk) || (mk == pk && mi < pi);
            bool low = ((t & j) == 0);
            if ((cmp_mp == want) != low) { mk = pk; mi = pi; }
        }
    }

    // Gather box by sorted index, xywh -> xyxy (mul by 0.5 exact).
    {
        float cx = db[mi*6+0], cy = db[mi*6+1];
        float w  = db[mi*6+2], h  = db[mi*6+3];
        float hw = __fmul_rn(w, 0.5f), hh = __fmul_rn(h, 0.5f);
        sboxes[(size_t)b*NBOX + t] = make_float4(__fsub_rn(cx,hw), __fsub_rn(cy,hh),
                                                 __fadd_rn(cx,hw), __fadd_rn(cy,hh));
    }
    int cnt = __syncthreads_count(st > CONF_THR);
    if (t == 0) nv_out[b] = cnt;
}

// ---------------- Kernel 2: pairwise-IoU suppression bitmask rows ----------------
__global__ __launch_bounds__(256) void iou_mask_kernel(
    const float4* __restrict__ sboxes, // (B,1024)
    const int* __restrict__ nv,        // (B,)
    u64* __restrict__ mask)            // (B,1024,16) bit j of row i: j>i && IoU>thr
{
    const int b  = blockIdx.y;
    const int i0 = blockIdx.x * RPB;
    const int nvB = nv[b];
    if (i0 >= nvB) return;             // rows never read by scan
    const int tid = threadIdx.x;
    const int lane = tid & 63, wv = tid >> 6;

    const float4* sb = sboxes + (size_t)b * NBOX;
    float4 bi[RPB]; float ai[RPB];
    #pragma unroll
    for (int r = 0; r < RPB; ++r) {
        bi[r] = sb[min(i0 + r, NBOX - 1)];
        ai[r] = __fmul_rn(__fsub_rn(bi[r].z, bi[r].x), __fsub_rn(bi[r].w, bi[r].y));
    }
    u64* rowbase = mask + ((size_t)b * NBOX + i0) * 16;

    for (int c = 0; c < 4; ++c) {
        const int j = c * 256 + tid;
        const float4 bj = sb[j];
        const float aj = __fmul_rn(__fsub_rn(bj.z, bj.x), __fsub_rn(bj.w, bj.y));
        #pragma unroll
        for (int r = 0; r < RPB; ++r) {
            const int i = i0 + r;
            if (i >= nvB) break;       // uniform across block
            float lx = fmaxf(bi[r].x, bj.x), ly = fmaxf(bi[r].y, bj.y);
            float rx = fminf(bi[r].z, bj.z), ry = fminf(bi[r].w, bj.w);
            float iw = fmaxf(__fsub_rn(rx, lx), 0.0f);
            float ih = fmaxf(__fsub_rn(ry, ly), 0.0f);
            float inter = __fmul_rn(iw, ih);
            float denom = __fadd_rn(__fsub_rn(__fadd_rn(ai[r], aj), inter), 1e-7f);
            bool pred = (j > i) && (__fdiv_rn(inter, denom) > IOU_THR);
            u64 m = __ballot(pred);
            if (lane == 0) rowbase[(size_t)r * 16 + c * 4 + wv] = m;
        }
    }
}

// ---------------- Kernel 3: greedy scan — LDS-staged chunks + early exit at 100 keeps ----------------
__global__ __launch_bounds__(1024) void scan_kernel(
    const float4* __restrict__ sboxes,
    const u64* __restrict__ mask,
    const int* __restrict__ nv,
    float4* __restrict__ sel,          // (B,100)
    int* __restrict__ nkeep)           // (B,)
{
    const int b = blockIdx.x, tid = threadIdx.x;
    const int lane = tid & 63;
    const int nvB = nv[b];
    const u64* mb = mask + (size_t)b * NBOX * 16;

    __shared__ u64 lm[CHUNK * 16];     // 32 KB staged mask rows
    __shared__ int s_stop;

    u64 sw = 0, kw = 0;                // wave0: lane l (<16) holds supp/keep word l
    int kcnt = 0;
    if (tid == 0) s_stop = 0;

    for (int base = 0; base < nvB; base += CHUNK) {
        const int cn = min(CHUNK, nvB - base);
        // cooperative coalesced stage: HBM/L3 latency paid once per chunk
        for (int idx = tid; idx < cn * 16; idx += 1024)
            lm[idx] = mb[(size_t)base * 16 + idx];
        __syncthreads();

        if (tid < 64) {
            u64 pre[8];
            #pragma unroll
            for (int u = 0; u < 8; ++u)
                pre[u] = (u < cn && lane < 16) ? lm[u * 16 + lane] : 0ull;
            for (int r0 = 0; r0 < cn && kcnt < KTOP; r0 += 8) {
                #pragma unroll
                for (int u = 0; u < 8; ++u) {   // static indexing: pre[] stays in regs
                    const int r = r0 + u;
                    u64 row = pre[u];
                    const int rp = r + 8;
                    pre[u] = (rp < cn && lane < 16) ? lm[rp * 16 + lane] : 0ull;
                    if (r < cn && kcnt < KTOP) {
                        const int i = base + r;
                        const int wsel = i >> 6;
                        u64 sword = __shfl(sw, wsel);          // uniform result
                        if (!((sword >> (i & 63)) & 1ull)) {   // not suppressed -> keep
                            sw |= row;
                            if (lane == wsel) kw |= (1ull << (i & 63));
                            ++kcnt;                            // wave-uniform
                        }
                    }
                }
            }
            if (tid == 0 && kcnt >= KTOP) s_stop = 1;  // first 100 kept == top-K: rest is dead
        }
        __syncthreads();
        if (s_stop) break;             // uniform across block
    }

    if (tid < 64) {
        // wave-parallel compaction: rank = exclusive popcount prefix
        int cnt = (lane < 16) ? __popcll(kw) : 0;
        int pfx = cnt;
        #pragma unroll
        for (int d = 1; d < 16; d <<= 1) { int t2 = __shfl_up(pfx, d); if (lane >= d) pfx += t2; }
        const int excl = pfx - cnt;
        const int total = __shfl(pfx, 15);     // == kcnt <= 100

        const float4* sb = sboxes + (size_t)b * NBOX;
        float4* selb = sel + (size_t)b * KTOP;
        for (int w = 0; w < 16; ++w) {
            u64 kwW = __shfl(kw, w);
            int bR  = __shfl(excl, w);
            if ((kwW >> lane) & 1ull) {
                int rank = bR + __popcll(kwW & ((1ull << lane) - 1ull));
                if (rank < KTOP) selb[rank] = sb[w * 64 + lane];
            }
        }
        for (int r = total + lane; r < KTOP; r += 64) selb[r] = make_float4(0,0,0,0);
        if (lane == 0) nkeep[b] = total < KTOP ? total : KTOP;
    }
}

// ---------------- Kernel 4: ROI pool + MLP, G ROIs/block for W reuse ----------------
__global__ __launch_bounds__(256) void roi_mlp_kernel(
    const float* __restrict__ x,          // (B,3,640,640)
    const float4* __restrict__ sel,       // (B,100)
    const int* __restrict__ nkeep,        // (B,)
    const float* __restrict__ W1, const float* __restrict__ b1,
    const float* __restrict__ W2, const float* __restrict__ b2,
    const float* __restrict__ W3, const float* __restrict__ b3,
    float* __restrict__ out)              // (B,100,4)
{
    const int b = blockIdx.y, k0 = blockIdx.x * G, tid = threadIdx.x;
    __shared__ float crop[G][147];
    __shared__ float feat[G][255];
    __shared__ float hb[G][128];
    const int nvB = nkeep[b];
    const float4* selb = sel + (size_t)b * KTOP;

    for (int task = tid; task < G * 147; task += 256) {
        int g = task / 147, r = task - g * 147;
        int c = r / 49, rr = r - c * 49;
        int py = rr / 7, px = rr - py * 7;
        float4 bb = selb[k0 + g];
        float fx = __fadd_rn(bb.x, __fdiv_rn(__fmul_rn(__fsub_rn(bb.z, bb.x), (float)px + 0.5f), 7.0f));
        float fy = __fadd_rn(bb.y, __fdiv_rn(__fmul_rn(__fsub_rn(bb.w, bb.y), (float)py + 0.5f), 7.0f));
        int xi = (int)fminf(fmaxf(fx, 0.0f), 639.0f);
        int yi = (int)fminf(fmaxf(fy, 0.0f), 639.0f);
        crop[g][r] = x[(((size_t)b * 3 + c) * 640 + yi) * 640 + xi];
    }
    __syncthreads();

    if (tid < 255) {                       // layer 1: 147 -> 255, no activation
        float a0 = b1[tid], a1 = a0, a2 = a0, a3 = a0;
        for (int i = 0; i < 147; ++i) {
            float w = W1[i * 255 + tid];
            a0 += crop[0][i] * w; a1 += crop[1][i] * w;
            a2 += crop[2][i] * w; a3 += crop[3][i] * w;
        }
        feat[0][tid] = a0; feat[1][tid] = a1; feat[2][tid] = a2; feat[3][tid] = a3;
    }
    __syncthreads();

    {                                      // layer 2: 255 -> 128, relu
        const int col = tid & 127, g0 = (tid >> 7) * 2;
        float a0 = b2[col], a1 = a0;
        for (int i = 0; i < 255; ++i) {
            float w = W2[i * 128 + col];
            a0 += feat[g0][i] * w; a1 += feat[g0 + 1][i] * w;
        }
        hb[g0][col] = fmaxf(a0, 0.0f); hb[g0 + 1][col] = fmaxf(a1, 0.0f);
    }
    __syncthreads();

    if (tid < 4 * G) {                     // layer 3: 128 -> 4
        const int g = tid >> 2, o = tid & 3;
        float acc = b3[o];
        for (int i = 0; i < 128; ++i) acc += hb[g][i] * W3[i * 4 + o];
        const int k = k0 + g;
        out[((size_t)b * KTOP + k) * 4 + o] = (k < nvB) ? acc : 0.0f;
    }
}

extern "C" void kernel_launch(void* const* d_in, const int* in_sizes, int n_in,
                              void* d_out, int out_size, void* d_ws, size_t ws_size,
                              hipStream_t stream) {
    const float* x    = (const float*)d_in[0];
    const float* dets = (const float*)d_in[1];
    const float* W1   = (const float*)d_in[2];
    const float* b1   = (const float*)d_in[3];
    const float* W2   = (const float*)d_in[4];
    const float* b2   = (const float*)d_in[5];
    const float* W3   = (const float*)d_in[6];
    const float* b3   = (const float*)d_in[7];
    float* out = (float*)d_out;

    const int B = in_sizes[1] / (NBOX * 6);   // 16

    // workspace layout (16B-aligned chunks)
    float4* sboxes = (float4*)d_ws;                       // B*1024 float4 = 256 KB
    float4* sel    = sboxes + (size_t)B * NBOX;           // B*100  float4 = 25.6 KB
    u64*    mask   = (u64*)(sel + (size_t)B * KTOP);      // B*1024*16 u64 = 2 MB
    int*    nv     = (int*)(mask + (size_t)B * NBOX * 16);
    int*    nkeep  = nv + B;

    sort_kernel<<<B, NBOX, 0, stream>>>(dets, sboxes, nv);

    dim3 gmask(NBOX / RPB, B);
    iou_mask_kernel<<<gmask, 256, 0, stream>>>(sboxes, nv, mask);

    scan_kernel<<<B, 1024, 0, stream>>>(sboxes, mask, nv, sel, nkeep);

    dim3 groi(KTOP / G, B);
    roi_mlp_kernel<<<groi, 256, 0, stream>>>(x, sel, nkeep,
                                             W1, b1, W2, b2, W3, b3, out);
}